// Round 23
// baseline (100.184 us; speedup 1.0000x reference)
//
#include <hip/hip_runtime.h>

#define HEADS 4
#define OUT_CH 16
#define CCH 64            // HEADS*OUT_CH
#define IN_CH 128
#define NEG_SLOPE 0.2f
#define CAP 48            // slots per dest (max degree ~35)
#define CAPB 5120         // slots per coarse bucket (mean 4340, +12 sigma)
#define TILE_A 2048       // edges per phase-A block
#define BSTRIDE 32        // bcur padding: one line per bucket counter

typedef unsigned int       uint32;
typedef unsigned long long u64;
typedef unsigned short     u16;
typedef __attribute__((ext_vector_type(8))) short short8;
typedef __attribute__((ext_vector_type(4))) float f32x4;
typedef __attribute__((ext_vector_type(2))) float f32x2;

__device__ __forceinline__ uint32 bf16_rne(float f) {
    uint32 u = __float_as_uint(f);
    return (u + 0x7fffu + ((u >> 16) & 1u)) >> 16;
}

// ---------------------------------------------------------------------------
// Pre kernel (1 block): build wTg (bf16 W^T), wXg (att-weighted extension
// columns for the d_i/d_j MFMA), zero bcur.
// ---------------------------------------------------------------------------
__global__ __launch_bounds__(256) void k_pre(const float* __restrict__ w,
                                             const float* __restrict__ att,
                                             u16* __restrict__ wTg,
                                             u16* __restrict__ wXg,
                                             int* __restrict__ bcur, int NBUK) {
    int t = threadIdx.x;
    int c = t & 63, half = t >> 6;
    #pragma unroll
    for (int kk = 0; kk < 32; ++kk) {
        int k = half * 32 + kk;
        wTg[c * 128 + k] = (u16)bf16_rne(w[k * CCH + c]);
    }
    int j = t & 7, h = j & 3, kb = t >> 3;
    const float* ab = att + h * (2 * OUT_CH) + ((j >= 4) ? OUT_CH : 0);
    #pragma unroll
    for (int kk = 0; kk < 4; ++kk) {
        int k = kb * 4 + kk;
        float s = 0.f;
        #pragma unroll
        for (int cc = 0; cc < 16; ++cc)
            s = fmaf(w[k * CCH + h * OUT_CH + cc], ab[cc], s);
        wXg[j * 128 + k] = (u16)bf16_rne(s);
    }
    for (int i = t; i < 8 * 128; i += 256) wXg[8 * 128 + i] = 0;
    for (int i = t; i < NBUK * BSTRIDE; i += 256) bcur[i] = 0;
}

// ---------------------------------------------------------------------------
// FAT kernel: blocks [0, GB): LDS-free MFMA GEMM, wave = one 16-row tile.
//   h stored as TWO PLANES h0/h1 (N x 32 ch each, 3.2 MB -> fits XCD L2).
//   d_i/d_j produced by 5th B-frag (wXg) MFMA — no shuffles.
// blocks [GB, ..): PHASE A pure partition (R21-verified).
// ---------------------------------------------------------------------------
__global__ __launch_bounds__(256) void k_fat(const float* __restrict__ x,
                                             const u16* __restrict__ wTg,
                                             const u16* __restrict__ wXg,
                                             u16* __restrict__ h0,
                                             u16* __restrict__ h1,
                                             float* __restrict__ d_i,
                                             float* __restrict__ d_j,
                                             const int* __restrict__ rows,
                                             const int* __restrict__ cols,
                                             int* __restrict__ bcur,
                                             uint32* __restrict__ bucketbuf,
                                             int N, int E, int GB, int NBUK) {
    int t = threadIdx.x;

    if ((int)blockIdx.x < GB) {
        // ---------------- GEMM path ----------------
        int lane = t & 63;
        int col = lane & 15, g = (lane >> 4) * 8;
        int tile = blockIdx.x * 4 + (t >> 6);
        int ntiles = (N + 15) >> 4;
        if (tile >= ntiles) return;

        int r0 = tile * 16 + (lane & 15);
        if (r0 >= N) r0 = N - 1;
        const float* xp = x + (size_t)r0 * IN_CH + g;
        float4 cu[8];
        #pragma unroll
        for (int kc = 0; kc < 4; ++kc) {
            cu[kc * 2]     = *(const float4*)(xp + kc * 32);
            cu[kc * 2 + 1] = *(const float4*)(xp + kc * 32 + 4);
        }

        short8 bfrag[4][4], bfrag5[4];
        #pragma unroll
        for (int nt = 0; nt < 4; ++nt)
            #pragma unroll
            for (int kc = 0; kc < 4; ++kc)
                bfrag[nt][kc] = *(const short8*)&wTg[(nt * 16 + col) * 128 + kc * 32 + g];
        #pragma unroll
        for (int kc = 0; kc < 4; ++kc)
            bfrag5[kc] = *(const short8*)&wXg[col * 128 + kc * 32 + g];

        short8 af[4];
        #pragma unroll
        for (int kc = 0; kc < 4; ++kc) {
            float4 u = cu[kc * 2], v = cu[kc * 2 + 1];
            short8 s;
            s[0] = (short)bf16_rne(u.x); s[1] = (short)bf16_rne(u.y);
            s[2] = (short)bf16_rne(u.z); s[3] = (short)bf16_rne(u.w);
            s[4] = (short)bf16_rne(v.x); s[5] = (short)bf16_rne(v.y);
            s[6] = (short)bf16_rne(v.z); s[7] = (short)bf16_rne(v.w);
            af[kc] = s;
        }

        f32x4 acc[4] = {{0.f,0.f,0.f,0.f},{0.f,0.f,0.f,0.f},
                        {0.f,0.f,0.f,0.f},{0.f,0.f,0.f,0.f}};
        f32x4 accX = {0.f, 0.f, 0.f, 0.f};
        #pragma unroll
        for (int kc = 0; kc < 4; ++kc) {
            #pragma unroll
            for (int nt = 0; nt < 4; ++nt)
                acc[nt] = __builtin_amdgcn_mfma_f32_16x16x32_bf16(
                    af[kc], bfrag[nt][kc], acc[nt], 0, 0, 0);
            accX = __builtin_amdgcn_mfma_f32_16x16x32_bf16(
                af[kc], bfrag5[kc], accX, 0, 0, 0);
        }

        int rb = tile * 16;
        #pragma unroll
        for (int nt = 0; nt < 4; ++nt) {
            u16* hp = (nt < 2) ? h0 : h1;
            int cc = (nt & 1) * 16 + col;
            #pragma unroll
            for (int r = 0; r < 4; ++r) {
                int row = rb + (lane >> 4) * 4 + r;
                if (row < N)
                    hp[(size_t)row * 32 + cc] = (u16)bf16_rne(acc[nt][r]);
            }
        }
        if (col < 8) {
            #pragma unroll
            for (int r = 0; r < 4; ++r) {
                int row = rb + (lane >> 4) * 4 + r;
                if (row < N) {
                    if (col < 4) d_i[row * HEADS + col] = accX[r];
                    else         d_j[row * HEADS + (col - 4)] = accX[r];
                }
            }
        }
    } else {
        // ---------------- PHASE A: pure partition ----------------
        __shared__ int lcnt[256];
        __shared__ int lofs[256];
        __shared__ int lbase[256];
        __shared__ int wsum[4];
        __shared__ uint32 recbuf[TILE_A];
        __shared__ int    gbuf[TILE_A];
        int b = (int)blockIdx.x - GB;
        int e0 = b * TILE_A;
        int tot = E + N;
        int lane = t & 63, wid = t >> 6;

        lcnt[t] = 0;
        __syncthreads();

        int mybkt[8], myrank[8];
        uint32 myrec[8];
        #pragma unroll
        for (int i = 0; i < 8; ++i) {
            int e = e0 + i * 256 + t;
            if (e < tot) {
                int c = (e < E) ? cols[e] : (e - E);
                int r = (e < E) ? rows[e] : c;
                int bk = c >> 8;
                mybkt[i] = bk;
                myrec[i] = (uint32)r | ((uint32)(c & 255) << 17);
                myrank[i] = atomicAdd(&lcnt[bk], 1);
            } else {
                mybkt[i] = -1;
            }
        }
        __syncthreads();

        int v = lcnt[t];
        int sc = v;
        #pragma unroll
        for (int off = 1; off < 64; off <<= 1) {
            int u = __shfl_up(sc, off);
            if (lane >= off) sc += u;
        }
        if (lane == 63) wsum[wid] = sc;
        __syncthreads();
        int wb = 0;
        for (int j = 0; j < wid; ++j) wb += wsum[j];
        lofs[t] = wb + sc - v;
        if (t < NBUK && v > 0)
            lbase[t] = atomicAdd(&bcur[t * BSTRIDE], v);
        __syncthreads();

        #pragma unroll
        for (int i = 0; i < 8; ++i) {
            if (mybkt[i] < 0) continue;
            int bk = mybkt[i];
            int slot = lofs[bk] + myrank[i];
            int bpos = lbase[bk] + myrank[i];
            recbuf[slot] = myrec[i];
            gbuf[slot] = (bpos < CAPB) ? (bk * CAPB + bpos) : -1;
        }
        __syncthreads();

        int nrec = tot - e0;
        if (nrec > TILE_A) nrec = TILE_A;
        for (int sidx = t; sidx < nrec; sidx += 256) {
            int gp = gbuf[sidx];
            if (gp >= 0) bucketbuf[gp] = recbuf[sidx];
        }
    }
}

// ---------------------------------------------------------------------------
// PHASE B: block b = bucket b. For each 4 B record: gather d_i[row] (L2),
// d_j from LDS, softmax ONCE per edge, pack u64 {row:17, 4x11-bit alpha},
// LDS-rank into 96 KB window, flush coalesced to srec + write cur.
// ---------------------------------------------------------------------------
__global__ __launch_bounds__(256) void k_bucket(const int* __restrict__ bcur,
                                                const uint32* __restrict__ bucketbuf,
                                                const float* __restrict__ d_i,
                                                const float* __restrict__ d_j,
                                                u64* __restrict__ srec,
                                                int* __restrict__ cur, int N) {
    __shared__ u64 win[256 * CAP];   // 96 KB
    __shared__ int lcur[256];
    __shared__ float4 djl[256];      // 4 KB
    int t = threadIdx.x;
    int b = blockIdx.x;
    int c0 = b << 8;

    lcur[t] = 0;
    int cidx = c0 + t;
    djl[t] = (cidx < N) ? *(const float4*)(d_j + (size_t)cidx * HEADS)
                        : make_float4(0.f, 0.f, 0.f, 0.f);
    __syncthreads();

    int cnt = bcur[b * BSTRIDE];
    if (cnt > CAPB) cnt = CAPB;
    const uint32* bb = bucketbuf + (size_t)b * CAPB;
    for (int i = t; i < cnt; i += 256) {
        uint32 rec = bb[i];
        int row  = rec & 0x1FFFF;
        int crel = (rec >> 17) & 255;
        float4 di4 = *(const float4*)(d_i + (size_t)row * HEADS);
        float4 dj4 = djl[crel];
        float l0 = di4.x + dj4.x, l1 = di4.y + dj4.y;
        float l2 = di4.z + dj4.z, l3 = di4.w + dj4.w;
        l0 = l0 > 0.f ? l0 : NEG_SLOPE * l0;
        l1 = l1 > 0.f ? l1 : NEG_SLOPE * l1;
        l2 = l2 > 0.f ? l2 : NEG_SLOPE * l2;
        l3 = l3 > 0.f ? l3 : NEG_SLOPE * l3;
        float m = fmaxf(fmaxf(l0, l1), fmaxf(l2, l3));
        float e0 = __expf(l0 - m), e1 = __expf(l1 - m);
        float e2 = __expf(l2 - m), e3 = __expf(l3 - m);
        float inv = 1.f / (e0 + e1 + e2 + e3);
        uint32 q0 = (uint32)(e0 * inv * 2047.f + 0.5f);
        uint32 q1 = (uint32)(e1 * inv * 2047.f + 0.5f);
        uint32 q2 = (uint32)(e2 * inv * 2047.f + 0.5f);
        uint32 q3 = (uint32)(e3 * inv * 2047.f + 0.5f);
        u64 prec = (u64)(uint32)row
                 | ((u64)q0 << 17) | ((u64)q1 << 28)
                 | ((u64)q2 << 39) | ((u64)q3 << 50);
        int pos = atomicAdd(&lcur[crel], 1);
        if (pos < CAP)
            win[crel * CAP + pos] = prec;
    }
    __syncthreads();

    int nd = N - c0;
    if (nd > 256) nd = 256;
    int nent = nd * CAP;
    u64* dst = srec + (size_t)c0 * CAP;
    for (int i = t; i < nent; i += 256) dst[i] = win[i];
    if (t < nd) {
        int v = lcur[t];
        cur[c0 + t] = (v > CAP) ? CAP : v;
    }
}

// ---------------------------------------------------------------------------
// Accumulate (run TWICE, half=0/1): 4 dests/wave, 16 lanes/dest, 2 ch/lane.
// h-plane for the pass = 3.2 MB -> L2-resident; srec/out nontemporal.
// ---------------------------------------------------------------------------
__global__ __launch_bounds__(256) void k_accum(const int* __restrict__ cur,
                                               const u64* __restrict__ srec,
                                               const u16* __restrict__ hp,
                                               const float* __restrict__ bias,
                                               float* __restrict__ out,
                                               int N, int half) {
    int t = threadIdx.x;
    int wid = t >> 6, lane = t & 63;
    int g = lane >> 4, sub = lane & 15;
    int node = blockIdx.x * 16 + wid * 4 + g;
    int c = (node < N) ? node : N - 1;

    int dg = cur[c];
    if (dg > CAP) dg = CAP;
    size_t s = (size_t)c * CAP;
    int md = dg;
    md = max(md, __shfl_xor(md, 16));
    md = max(md, __shfl_xor(md, 32));

    int ch0 = half * 32 + sub * 2;          // global channel of this lane
    int shift = 17 + 11 * (ch0 >> 4);       // head field in the record
    float a0 = 0.f, a1 = 0.f;

    #pragma unroll 8
    for (int r = 0; r < md; ++r) {
        size_t idx = s + ((r < dg) ? r : (dg - 1));
        u64 rec = __builtin_nontemporal_load(srec + idx);
        int row = (int)((uint32)rec & 0x1FFFFu);
        float a = (float)((uint32)(rec >> shift) & 0x7FFu) * (1.f / 2047.f);
        if (r >= dg) a = 0.f;
        uint32 hb = *(const uint32*)(hp + (size_t)row * 32 + sub * 2);
        a0 = fmaf(__uint_as_float(hb << 16),         a, a0);
        a1 = fmaf(__uint_as_float(hb & 0xffff0000u), a, a1);
    }

    if (node < N) {
        f32x2 o;
        o.x = a0 + bias[ch0];
        o.y = a1 + bias[ch0 + 1];
        __builtin_nontemporal_store(o, (f32x2*)(out + (size_t)node * CCH + ch0));
    }
}

extern "C" void kernel_launch(void* const* d_in, const int* in_sizes, int n_in,
                              void* d_out, int out_size, void* d_ws, size_t ws_size,
                              hipStream_t stream) {
    const float* x    = (const float*)d_in[0];
    const int*   ei   = (const int*)  d_in[1];
    const float* w    = (const float*)d_in[2];
    const float* att  = (const float*)d_in[3];
    const float* bias = (const float*)d_in[4];
    float* out = (float*)d_out;

    int N = in_sizes[0] / IN_CH;
    int E = in_sizes[1] / 2;
    const int* rows = ei;
    const int* cols = ei + E;
    int total_e = E + N;
    int NBUK = (N + 255) >> 8;                   // 196 for N=50000

    char* ws = (char*)d_ws;
    auto carve = [&](size_t bytes) {
        char* p = ws;
        ws += (bytes + 255) & ~(size_t)255;
        return p;
    };
    u16*    h0        = (u16*)   carve((size_t)N * 32 * 2);           // 3.2 MB
    u16*    h1        = (u16*)   carve((size_t)N * 32 * 2);           // 3.2 MB
    float*  di        = (float*) carve((size_t)N * HEADS * 4);        // 0.8 MB
    float*  dj        = (float*) carve((size_t)N * HEADS * 4);        // 0.8 MB
    int*    cur       = (int*)   carve((size_t)N * 4);                // 0.2 MB
    int*    bcur      = (int*)   carve((size_t)NBUK * BSTRIDE * 4);
    u64*    srec      = (u64*)   carve((size_t)N * CAP * 8);          // 19.2 MB
    u16*    wTg       = (u16*)   carve((size_t)64 * 128 * 2);         // 16 KB
    u16*    wXg       = (u16*)   carve((size_t)16 * 128 * 2);         // 4 KB
    uint32* bucketbuf = (uint32*)carve((size_t)NBUK * CAPB * 4);      // 4 MB

    int ntiles = (N + 15) >> 4;
    int GB = (ntiles + 3) / 4;                   // gemm blocks: 1 tile/wave
    int AB = (total_e + TILE_A - 1) / TILE_A;    // phase-A blocks
    int NACC = (N + 15) / 16;

    k_pre<<<1, 256, 0, stream>>>(w, att, wTg, wXg, bcur, NBUK);
    k_fat<<<GB + AB, 256, 0, stream>>>(x, wTg, wXg, h0, h1, di, dj, rows, cols,
                                       bcur, bucketbuf, N, E, GB, NBUK);
    k_bucket<<<NBUK, 256, 0, stream>>>(bcur, bucketbuf, di, dj, srec, cur, N);
    k_accum<<<NACC, 256, 0, stream>>>(cur, srec, h0, bias, out, N, 0);
    k_accum<<<NACC, 256, 0, stream>>>(cur, srec, h1, bias, out, N, 1);
}

// Round 24
// 80.393 us; speedup vs baseline: 1.2462x; 1.2462x over previous
//
#include <hip/hip_runtime.h>

#define HEADS 4
#define OUT_CH 16
#define CCH 64            // HEADS*OUT_CH
#define IN_CH 128
#define NEG_SLOPE 0.2f
#define CAP 48            // slots per dest (max degree ~35)
#define CAPB 5120         // slots per coarse bucket (mean 4340, +12 sigma)
#define TILE_A 2048       // edges per phase-A block
#define BSTRIDE 32        // bcur padding: one line per bucket counter

typedef unsigned int       uint32;
typedef unsigned long long u64;
typedef unsigned short     u16;
typedef __attribute__((ext_vector_type(8))) short short8;
typedef __attribute__((ext_vector_type(4))) float f32x4;

__device__ __forceinline__ uint32 bf16_rne(float f) {
    uint32 u = __float_as_uint(f);
    return (u + 0x7fffu + ((u >> 16) & 1u)) >> 16;
}

// ---------------------------------------------------------------------------
// Pre kernel (1 block): build wTg (bf16 W^T), wXg (att-weighted extension
// columns for the d_i/d_j MFMA), zero bcur.
// ---------------------------------------------------------------------------
__global__ __launch_bounds__(256) void k_pre(const float* __restrict__ w,
                                             const float* __restrict__ att,
                                             u16* __restrict__ wTg,
                                             u16* __restrict__ wXg,
                                             int* __restrict__ bcur, int NBUK) {
    int t = threadIdx.x;
    int c = t & 63, half = t >> 6;
    #pragma unroll
    for (int kk = 0; kk < 32; ++kk) {
        int k = half * 32 + kk;
        wTg[c * 128 + k] = (u16)bf16_rne(w[k * CCH + c]);
    }
    int j = t & 7, h = j & 3, kb = t >> 3;
    const float* ab = att + h * (2 * OUT_CH) + ((j >= 4) ? OUT_CH : 0);
    #pragma unroll
    for (int kk = 0; kk < 4; ++kk) {
        int k = kb * 4 + kk;
        float s = 0.f;
        #pragma unroll
        for (int cc = 0; cc < 16; ++cc)
            s = fmaf(w[k * CCH + h * OUT_CH + cc], ab[cc], s);
        wXg[j * 128 + k] = (u16)bf16_rne(s);
    }
    for (int i = t; i < 8 * 128; i += 256) wXg[8 * 128 + i] = 0;
    for (int i = t; i < NBUK * BSTRIDE; i += 256) bcur[i] = 0;
}

// ---------------------------------------------------------------------------
// FAT kernel: blocks [0, GB): LDS-free MFMA GEMM, wave = one 16-row tile.
//   h_bf[N][64] single layout; d_i/d_j via 5th B-frag MFMA.
// blocks [GB, ..): PHASE A pure partition (R21-verified), 4 B records.
// ---------------------------------------------------------------------------
__global__ __launch_bounds__(256) void k_fat(const float* __restrict__ x,
                                             const u16* __restrict__ wTg,
                                             const u16* __restrict__ wXg,
                                             u16* __restrict__ h_bf,
                                             float* __restrict__ d_i,
                                             float* __restrict__ d_j,
                                             const int* __restrict__ rows,
                                             const int* __restrict__ cols,
                                             int* __restrict__ bcur,
                                             uint32* __restrict__ bucketbuf,
                                             int N, int E, int GB, int NBUK) {
    int t = threadIdx.x;

    if ((int)blockIdx.x < GB) {
        // ---------------- GEMM path ----------------
        int lane = t & 63;
        int col = lane & 15, g = (lane >> 4) * 8;
        int tile = blockIdx.x * 4 + (t >> 6);
        int ntiles = (N + 15) >> 4;
        if (tile >= ntiles) return;

        int r0 = tile * 16 + (lane & 15);
        if (r0 >= N) r0 = N - 1;
        const float* xp = x + (size_t)r0 * IN_CH + g;
        float4 cu[8];
        #pragma unroll
        for (int kc = 0; kc < 4; ++kc) {
            cu[kc * 2]     = *(const float4*)(xp + kc * 32);
            cu[kc * 2 + 1] = *(const float4*)(xp + kc * 32 + 4);
        }

        short8 bfrag[4][4], bfrag5[4];
        #pragma unroll
        for (int nt = 0; nt < 4; ++nt)
            #pragma unroll
            for (int kc = 0; kc < 4; ++kc)
                bfrag[nt][kc] = *(const short8*)&wTg[(nt * 16 + col) * 128 + kc * 32 + g];
        #pragma unroll
        for (int kc = 0; kc < 4; ++kc)
            bfrag5[kc] = *(const short8*)&wXg[col * 128 + kc * 32 + g];

        short8 af[4];
        #pragma unroll
        for (int kc = 0; kc < 4; ++kc) {
            float4 u = cu[kc * 2], v = cu[kc * 2 + 1];
            short8 s;
            s[0] = (short)bf16_rne(u.x); s[1] = (short)bf16_rne(u.y);
            s[2] = (short)bf16_rne(u.z); s[3] = (short)bf16_rne(u.w);
            s[4] = (short)bf16_rne(v.x); s[5] = (short)bf16_rne(v.y);
            s[6] = (short)bf16_rne(v.z); s[7] = (short)bf16_rne(v.w);
            af[kc] = s;
        }

        f32x4 acc[4] = {{0.f,0.f,0.f,0.f},{0.f,0.f,0.f,0.f},
                        {0.f,0.f,0.f,0.f},{0.f,0.f,0.f,0.f}};
        f32x4 accX = {0.f, 0.f, 0.f, 0.f};
        #pragma unroll
        for (int kc = 0; kc < 4; ++kc) {
            #pragma unroll
            for (int nt = 0; nt < 4; ++nt)
                acc[nt] = __builtin_amdgcn_mfma_f32_16x16x32_bf16(
                    af[kc], bfrag[nt][kc], acc[nt], 0, 0, 0);
            accX = __builtin_amdgcn_mfma_f32_16x16x32_bf16(
                af[kc], bfrag5[kc], accX, 0, 0, 0);
        }

        int rb = tile * 16;
        #pragma unroll
        for (int nt = 0; nt < 4; ++nt)
            #pragma unroll
            for (int r = 0; r < 4; ++r) {
                int row = rb + (lane >> 4) * 4 + r;
                if (row < N)
                    h_bf[(size_t)row * CCH + nt * 16 + col] =
                        (u16)bf16_rne(acc[nt][r]);
            }
        if (col < 8) {
            #pragma unroll
            for (int r = 0; r < 4; ++r) {
                int row = rb + (lane >> 4) * 4 + r;
                if (row < N) {
                    if (col < 4) d_i[row * HEADS + col] = accX[r];
                    else         d_j[row * HEADS + (col - 4)] = accX[r];
                }
            }
        }
    } else {
        // ---------------- PHASE A: pure partition ----------------
        __shared__ int lcnt[256];
        __shared__ int lofs[256];
        __shared__ int lbase[256];
        __shared__ int wsum[4];
        __shared__ uint32 recbuf[TILE_A];
        __shared__ int    gbuf[TILE_A];
        int b = (int)blockIdx.x - GB;
        int e0 = b * TILE_A;
        int tot = E + N;
        int lane = t & 63, wid = t >> 6;

        lcnt[t] = 0;
        __syncthreads();

        int mybkt[8], myrank[8];
        uint32 myrec[8];
        #pragma unroll
        for (int i = 0; i < 8; ++i) {
            int e = e0 + i * 256 + t;
            if (e < tot) {
                int c = (e < E) ? cols[e] : (e - E);
                int r = (e < E) ? rows[e] : c;
                int bk = c >> 8;
                mybkt[i] = bk;
                myrec[i] = (uint32)r | ((uint32)(c & 255) << 17);
                myrank[i] = atomicAdd(&lcnt[bk], 1);
            } else {
                mybkt[i] = -1;
            }
        }
        __syncthreads();

        int v = lcnt[t];
        int sc = v;
        #pragma unroll
        for (int off = 1; off < 64; off <<= 1) {
            int u = __shfl_up(sc, off);
            if (lane >= off) sc += u;
        }
        if (lane == 63) wsum[wid] = sc;
        __syncthreads();
        int wb = 0;
        for (int j = 0; j < wid; ++j) wb += wsum[j];
        lofs[t] = wb + sc - v;
        if (t < NBUK && v > 0)
            lbase[t] = atomicAdd(&bcur[t * BSTRIDE], v);
        __syncthreads();

        #pragma unroll
        for (int i = 0; i < 8; ++i) {
            if (mybkt[i] < 0) continue;
            int bk = mybkt[i];
            int slot = lofs[bk] + myrank[i];
            int bpos = lbase[bk] + myrank[i];
            recbuf[slot] = myrec[i];
            gbuf[slot] = (bpos < CAPB) ? (bk * CAPB + bpos) : -1;
        }
        __syncthreads();

        int nrec = tot - e0;
        if (nrec > TILE_A) nrec = TILE_A;
        for (int sidx = t; sidx < nrec; sidx += 256) {
            int gp = gbuf[sidx];
            if (gp >= 0) bucketbuf[gp] = recbuf[sidx];
        }
    }
}

// ---------------------------------------------------------------------------
// PHASE B: block b = bucket b. Gather d_i[row] (L2-resident), d_j from LDS,
// softmax ONCE per edge, pack u64 {row:17, 4x11-bit alpha}, LDS-rank into
// 96 KB window, flush coalesced to srec + write cur.
// ---------------------------------------------------------------------------
__global__ __launch_bounds__(256) void k_bucket(const int* __restrict__ bcur,
                                                const uint32* __restrict__ bucketbuf,
                                                const float* __restrict__ d_i,
                                                const float* __restrict__ d_j,
                                                u64* __restrict__ srec,
                                                int* __restrict__ cur, int N) {
    __shared__ u64 win[256 * CAP];   // 96 KB
    __shared__ int lcur[256];
    __shared__ float4 djl[256];      // 4 KB
    int t = threadIdx.x;
    int b = blockIdx.x;
    int c0 = b << 8;

    lcur[t] = 0;
    int cidx = c0 + t;
    djl[t] = (cidx < N) ? *(const float4*)(d_j + (size_t)cidx * HEADS)
                        : make_float4(0.f, 0.f, 0.f, 0.f);
    __syncthreads();

    int cnt = bcur[b * BSTRIDE];
    if (cnt > CAPB) cnt = CAPB;
    const uint32* bb = bucketbuf + (size_t)b * CAPB;
    for (int i = t; i < cnt; i += 256) {
        uint32 rec = bb[i];
        int row  = rec & 0x1FFFF;
        int crel = (rec >> 17) & 255;
        float4 di4 = *(const float4*)(d_i + (size_t)row * HEADS);
        float4 dj4 = djl[crel];
        float l0 = di4.x + dj4.x, l1 = di4.y + dj4.y;
        float l2 = di4.z + dj4.z, l3 = di4.w + dj4.w;
        l0 = l0 > 0.f ? l0 : NEG_SLOPE * l0;
        l1 = l1 > 0.f ? l1 : NEG_SLOPE * l1;
        l2 = l2 > 0.f ? l2 : NEG_SLOPE * l2;
        l3 = l3 > 0.f ? l3 : NEG_SLOPE * l3;
        float m = fmaxf(fmaxf(l0, l1), fmaxf(l2, l3));
        float e0 = __expf(l0 - m), e1 = __expf(l1 - m);
        float e2 = __expf(l2 - m), e3 = __expf(l3 - m);
        float inv = 1.f / (e0 + e1 + e2 + e3);
        uint32 q0 = (uint32)(e0 * inv * 2047.f + 0.5f);
        uint32 q1 = (uint32)(e1 * inv * 2047.f + 0.5f);
        uint32 q2 = (uint32)(e2 * inv * 2047.f + 0.5f);
        uint32 q3 = (uint32)(e3 * inv * 2047.f + 0.5f);
        u64 prec = (u64)(uint32)row
                 | ((u64)q0 << 17) | ((u64)q1 << 28)
                 | ((u64)q2 << 39) | ((u64)q3 << 50);
        int pos = atomicAdd(&lcur[crel], 1);
        if (pos < CAP)
            win[crel * CAP + pos] = prec;
    }
    __syncthreads();

    int nd = N - c0;
    if (nd > 256) nd = 256;
    int nent = nd * CAP;
    u64* dst = srec + (size_t)c0 * CAP;
    for (int i = t; i < nent; i += 256) dst[i] = win[i];
    if (t < nd) {
        int v = lcur[t];
        cur[c0 + t] = (v > CAP) ? CAP : v;
    }
}

// ---------------------------------------------------------------------------
// Accumulate (single pass, R16-proven form): 4 dests/wave, 16 lanes/dest,
// 4 ch/lane via uint2 loads; alphas pre-packed in srec; unroll 8.
// ---------------------------------------------------------------------------
__global__ __launch_bounds__(256) void k_accum(const int* __restrict__ cur,
                                               const u64* __restrict__ srec,
                                               const u16* __restrict__ h_bf,
                                               const float* __restrict__ bias,
                                               float* __restrict__ out, int N) {
    int t = threadIdx.x;
    int wid = t >> 6, lane = t & 63;
    int g = lane >> 4, sub = lane & 15;
    int node = blockIdx.x * 16 + wid * 4 + g;
    int c = (node < N) ? node : N - 1;

    int dg = cur[c];
    if (dg > CAP) dg = CAP;
    size_t s = (size_t)c * CAP;
    int md = dg;
    md = max(md, __shfl_xor(md, 16));
    md = max(md, __shfl_xor(md, 32));

    int shift = 17 + 11 * (sub >> 2);      // this lane's head field
    float a0 = 0.f, a1 = 0.f, a2 = 0.f, a3 = 0.f;

    #pragma unroll 8
    for (int r = 0; r < md; ++r) {
        size_t idx = s + ((r < dg) ? r : (dg - 1));
        u64 rec = __builtin_nontemporal_load(srec + idx);
        int row = (int)((uint32)rec & 0x1FFFFu);
        float a = (float)((uint32)(rec >> shift) & 0x7FFu) * (1.f / 2047.f);
        if (r >= dg) a = 0.f;
        uint2 hb = *(const uint2*)(h_bf + (size_t)row * CCH + sub * 4);
        a0 = fmaf(__uint_as_float(hb.x << 16),         a, a0);
        a1 = fmaf(__uint_as_float(hb.x & 0xffff0000u), a, a1);
        a2 = fmaf(__uint_as_float(hb.y << 16),         a, a2);
        a3 = fmaf(__uint_as_float(hb.y & 0xffff0000u), a, a3);
    }

    if (node < N) {
        float4 b = *(const float4*)(bias + sub * 4);
        float4 o = {a0 + b.x, a1 + b.y, a2 + b.z, a3 + b.w};
        *(float4*)(out + (size_t)node * CCH + sub * 4) = o;
    }
}

extern "C" void kernel_launch(void* const* d_in, const int* in_sizes, int n_in,
                              void* d_out, int out_size, void* d_ws, size_t ws_size,
                              hipStream_t stream) {
    const float* x    = (const float*)d_in[0];
    const int*   ei   = (const int*)  d_in[1];
    const float* w    = (const float*)d_in[2];
    const float* att  = (const float*)d_in[3];
    const float* bias = (const float*)d_in[4];
    float* out = (float*)d_out;

    int N = in_sizes[0] / IN_CH;
    int E = in_sizes[1] / 2;
    const int* rows = ei;
    const int* cols = ei + E;
    int total_e = E + N;
    int NBUK = (N + 255) >> 8;                   // 196 for N=50000

    char* ws = (char*)d_ws;
    auto carve = [&](size_t bytes) {
        char* p = ws;
        ws += (bytes + 255) & ~(size_t)255;
        return p;
    };
    u16*    h_bf      = (u16*)   carve((size_t)N * CCH * 2);          // 6.4 MB
    float*  di        = (float*) carve((size_t)N * HEADS * 4);        // 0.8 MB
    float*  dj        = (float*) carve((size_t)N * HEADS * 4);        // 0.8 MB
    int*    cur       = (int*)   carve((size_t)N * 4);                // 0.2 MB
    int*    bcur      = (int*)   carve((size_t)NBUK * BSTRIDE * 4);
    u64*    srec      = (u64*)   carve((size_t)N * CAP * 8);          // 19.2 MB
    u16*    wTg       = (u16*)   carve((size_t)64 * 128 * 2);         // 16 KB
    u16*    wXg       = (u16*)   carve((size_t)16 * 128 * 2);         // 4 KB
    uint32* bucketbuf = (uint32*)carve((size_t)NBUK * CAPB * 4);      // 4 MB

    int ntiles = (N + 15) >> 4;
    int GB = (ntiles + 3) / 4;                   // gemm blocks: 1 tile/wave
    int AB = (total_e + TILE_A - 1) / TILE_A;    // phase-A blocks
    int NACC = (N + 15) / 16;

    k_pre<<<1, 256, 0, stream>>>(w, att, wTg, wXg, bcur, NBUK);
    k_fat<<<GB + AB, 256, 0, stream>>>(x, wTg, wXg, h_bf, di, dj, rows, cols,
                                       bcur, bucketbuf, N, E, GB, NBUK);
    k_bucket<<<NBUK, 256, 0, stream>>>(bcur, bucketbuf, di, dj, srec, cur, N);
    k_accum<<<NACC, 256, 0, stream>>>(cur, srec, h_bf, bias, out, N);
}